// Round 1
// baseline (282.044 us; speedup 1.0000x reference)
//
#include <hip/hip_runtime.h>

#define SEQ   1024
#define HEADS 12
#define CDIM  768
#define BATCH 8
#define MROWS (BATCH*SEQ)

typedef __attribute__((ext_vector_type(8))) short bf16x8;
typedef __attribute__((ext_vector_type(4))) float f32x4;
typedef __attribute__((ext_vector_type(4))) float float4v;
typedef __attribute__((ext_vector_type(4))) short short4v;

__device__ __forceinline__ void gload_lds16(const void* g, void* l) {
  __builtin_amdgcn_global_load_lds(
      (const __attribute__((address_space(1))) unsigned int*)g,
      (__attribute__((address_space(3))) unsigned int*)l, 16, 0, 0);
}

__device__ __forceinline__ unsigned short f2bf(float f) {
  union { float f; unsigned u; } v; v.f = f;
  unsigned r = v.u + 0x7fff + ((v.u >> 16) & 1);
  return (unsigned short)(r >> 16);
}
__device__ __forceinline__ float bf2f(unsigned short b) {
  union { float f; unsigned u; } v; v.u = ((unsigned)b) << 16;
  return v.f;
}

// x [8192,768] f32 -> A_hilo [8192,1536] bf16 (hi | lo)
__global__ __launch_bounds__(256) void prep_x_kernel(const float* __restrict__ x,
                                                     short* __restrict__ A) {
  int i = blockIdx.x * 256 + threadIdx.x;      // 8192*192 threads, 4 elems each
  int r = i / 192;
  int c4 = (i % 192) * 4;
  float4v xv = *(const float4v*)(x + (size_t)r * 768 + c4);
  short4v hi, lo;
#pragma unroll
  for (int j = 0; j < 4; ++j) {
    unsigned short h = f2bf(xv[j]);
    hi[j] = (short)h;
    lo[j] = (short)f2bf(xv[j] - bf2f(h));
  }
  *(short4v*)(A + (size_t)r * 1536 + c4) = hi;
  *(short4v*)(A + (size_t)r * 1536 + 768 + c4) = lo;
}

// W_qkv [768,2304] f32 -> B2t [2304,1536] bf16 transposed (hi | lo)
__global__ __launch_bounds__(256) void prep_w_kernel(const float* __restrict__ W,
                                                     short* __restrict__ Bt) {
  __shared__ float tile[64][65];
  int k0 = blockIdx.x * 64;   // over 768
  int n0 = blockIdx.y * 64;   // over 2304
  int t = threadIdx.x;
#pragma unroll
  for (int it = 0; it < 16; ++it) {
    int r = it * 4 + (t >> 6);
    int c = t & 63;
    tile[r][c] = W[(size_t)(k0 + r) * 2304 + n0 + c];
  }
  __syncthreads();
#pragma unroll
  for (int it = 0; it < 16; ++it) {
    int nr = it * 4 + (t >> 6);
    int kc = t & 63;
    float v = tile[kc][nr];
    unsigned short h = f2bf(v);
    Bt[(size_t)(n0 + nr) * 1536 + k0 + kc] = (short)h;
    Bt[(size_t)(n0 + nr) * 1536 + 768 + k0 + kc] = (short)f2bf(v - bf2f(h));
  }
}

// W_proj [768,768] f32 -> Wpt [768,768] bf16 transposed (plain)
__global__ __launch_bounds__(256) void prep_wp_kernel(const float* __restrict__ W,
                                                      short* __restrict__ Bt) {
  __shared__ float tile[64][65];
  int k0 = blockIdx.x * 64;
  int n0 = blockIdx.y * 64;
  int t = threadIdx.x;
#pragma unroll
  for (int it = 0; it < 16; ++it) {
    int r = it * 4 + (t >> 6);
    int c = t & 63;
    tile[r][c] = W[(size_t)(k0 + r) * 768 + n0 + c];
  }
  __syncthreads();
#pragma unroll
  for (int it = 0; it < 16; ++it) {
    int nr = it * 4 + (t >> 6);
    int kc = t & 63;
    Bt[(size_t)(n0 + nr) * 768 + k0 + kc] = (short)f2bf(tile[kc][nr]);
  }
}

// Shared 128x128-tile GEMM, BK=64, 4 waves, 16x16x32 bf16 MFMA.
// MODE 1: qkv split GEMM (K=2304 logical over hi/lo thirds), scatter q/k/vT bf16.
// MODE 2: proj GEMM (K=768), write f32 + bias.
template <int MODE>
__global__ __launch_bounds__(256) void gemm_kernel(
    const short* __restrict__ A, const short* __restrict__ Bt,
    const float* __restrict__ bias,
    short* __restrict__ outQ, short* __restrict__ outK, short* __restrict__ outVT,
    float* __restrict__ outF) {
  const int ldA = (MODE == 1) ? 1536 : 768;
  const int ldB = (MODE == 1) ? 1536 : 768;
  const int Ktot = (MODE == 1) ? 2304 : 768;
  const int n0 = blockIdx.x * 128;
  const int m0 = blockIdx.y * 128;
  __shared__ short Als[128 * 64];
  __shared__ short Bls[128 * 64];
  const int tid = threadIdx.x;
  const int lane = tid & 63;
  const int w = tid >> 6;
  const int wr = (w >> 1) * 64;
  const int wc = (w & 1) * 64;
  f32x4 acc[4][4];
#pragma unroll
  for (int mi = 0; mi < 4; ++mi)
#pragma unroll
    for (int ni = 0; ni < 4; ++ni) acc[mi][ni] = (f32x4){0.f, 0.f, 0.f, 0.f};

  for (int k0 = 0; k0 < Ktot; k0 += 64) {
    int kA = k0, kB = k0;
    if (MODE == 1) {
      kA = (k0 < 1536) ? k0 : k0 - 1536;   // A thirds: hi | lo | hi
      kB = (k0 < 768) ? k0 : k0 - 768;     // B thirds: hi | hi | lo
    }
#pragma unroll
    for (int it = 0; it < 4; ++it) {
      int rbase = it * 32 + w * 8;
      int row = rbase + (lane >> 3);
      int ul = (lane & 7) ^ (row & 7);     // inverse-swizzled global unit
      gload_lds16(A + (size_t)(m0 + row) * ldA + kA + ul * 8, Als + rbase * 64);
      gload_lds16(Bt + (size_t)(n0 + row) * ldB + kB + ul * 8, Bls + rbase * 64);
    }
    __syncthreads();
#pragma unroll
    for (int kk = 0; kk < 2; ++kk) {
      bf16x8 af[4], bfv[4];
#pragma unroll
      for (int mi = 0; mi < 4; ++mi) {
        int row = wr + mi * 16 + (lane & 15);
        int off = (row * 128 + kk * 64 + (lane >> 4) * 16) ^ ((row & 7) << 4);
        af[mi] = *(const bf16x8*)((const char*)Als + off);
      }
#pragma unroll
      for (int ni = 0; ni < 4; ++ni) {
        int row = wc + ni * 16 + (lane & 15);
        int off = (row * 128 + kk * 64 + (lane >> 4) * 16) ^ ((row & 7) << 4);
        bfv[ni] = *(const bf16x8*)((const char*)Bls + off);
      }
#pragma unroll
      for (int mi = 0; mi < 4; ++mi)
#pragma unroll
        for (int ni = 0; ni < 4; ++ni)
          acc[mi][ni] = __builtin_amdgcn_mfma_f32_16x16x32_bf16(
              af[mi], bfv[ni], acc[mi][ni], 0, 0, 0);
    }
    __syncthreads();
  }
  // epilogue: C row=(lane>>4)*4+j, col=lane&15 within each 16x16 tile
#pragma unroll
  for (int mi = 0; mi < 4; ++mi)
#pragma unroll
    for (int ni = 0; ni < 4; ++ni)
#pragma unroll
      for (int j = 0; j < 4; ++j) {
        int row = m0 + wr + mi * 16 + ((lane >> 4) << 2) + j;
        int col = n0 + wc + ni * 16 + (lane & 15);
        float v = acc[mi][ni][j] + bias[col];
        if (MODE == 1) {
          int three = col / 768;
          int rem = col - three * 768;
          int h = rem >> 6, d = rem & 63;
          int b = row >> 10, n = row & 1023;
          unsigned short bv = f2bf(v);
          size_t bh = (size_t)(b * 12 + h);
          if (three == 0)      outQ[(bh * 1024 + n) * 64 + d] = (short)bv;
          else if (three == 1) outK[(bh * 1024 + n) * 64 + d] = (short)bv;
          else                 outVT[(bh * 64 + d) * 1024 + n] = (short)bv;
        } else {
          outF[(size_t)row * 768 + col] = v;
        }
      }
}

// Flash attention: grid (16 qblocks, 12 heads, 8 batch), 4 waves x 16 q-rows.
__global__ __launch_bounds__(256) void attn_kernel(
    const short* __restrict__ qb, const short* __restrict__ kb,
    const short* __restrict__ vtb, const float* __restrict__ pos,
    short* __restrict__ outb) {
  const int qblk = blockIdx.x, h = blockIdx.y, b = blockIdx.z;
  const int tid = threadIdx.x, lane = tid & 63, w = tid >> 6;
  const size_t bh = (size_t)(b * 12 + h);
  const short* Q = qb + bh * SEQ * 64;
  const short* K = kb + bh * SEQ * 64;
  const short* VT = vtb + bh * 64 * SEQ;
  const float* P = pos + (size_t)h * SEQ * SEQ;
  const int q0 = qblk * 64 + w * 16;

  __shared__ short kls[64 * 64];
  __shared__ short vls[64 * 64];
  __shared__ short pls[4][16 * 64];

  const int qrow = q0 + (lane & 15);
  bf16x8 qf0 = *(const bf16x8*)(Q + (size_t)qrow * 64 + (lane >> 4) * 8);
  bf16x8 qf1 = *(const bf16x8*)(Q + (size_t)qrow * 64 + 32 + (lane >> 4) * 8);

  f32x4 o[4];
#pragma unroll
  for (int t = 0; t < 4; ++t) o[t] = (f32x4){0.f, 0.f, 0.f, 0.f};
  float m[4] = {-1e30f, -1e30f, -1e30f, -1e30f};
  float lsum[4] = {0.f, 0.f, 0.f, 0.f};

  for (int kv0 = 0; kv0 < SEQ; kv0 += 64) {
#pragma unroll
    for (int it = 0; it < 2; ++it) {
      int rbase = w * 16 + it * 8;
      int row = rbase + (lane >> 3);
      int ul = (lane & 7) ^ (row & 7);
      gload_lds16(K + (size_t)(kv0 + row) * 64 + ul * 8, kls + rbase * 64);
      gload_lds16(VT + (size_t)row * SEQ + kv0 + ul * 8, vls + rbase * 64);
    }
    __syncthreads();

    f32x4 s[4];
#pragma unroll
    for (int t = 0; t < 4; ++t) {
      int row = t * 16 + (lane & 15);
      int sw = (row & 7) << 4;
      bf16x8 kf0 = *(const bf16x8*)((const char*)kls + ((row * 128 + (lane >> 4) * 16) ^ sw));
      bf16x8 kf1 = *(const bf16x8*)((const char*)kls + ((row * 128 + 64 + (lane >> 4) * 16) ^ sw));
      f32x4 z = (f32x4){0.f, 0.f, 0.f, 0.f};
      z = __builtin_amdgcn_mfma_f32_16x16x32_bf16(qf0, kf0, z, 0, 0, 0);
      s[t] = __builtin_amdgcn_mfma_f32_16x16x32_bf16(qf1, kf1, z, 0, 0, 0);
    }
#pragma unroll
    for (int t = 0; t < 4; ++t)
#pragma unroll
      for (int j = 0; j < 4; ++j) {
        int qr = ((lane >> 4) << 2) + j;
        int kvc = t * 16 + (lane & 15);
        float pv = P[(size_t)(q0 + qr) * SEQ + kv0 + kvc];
        s[t][j] = (s[t][j] + pv) * 0.125f;
      }
    float mx[4];
#pragma unroll
    for (int j = 0; j < 4; ++j)
      mx[j] = fmaxf(fmaxf(s[0][j], s[1][j]), fmaxf(s[2][j], s[3][j]));
#pragma unroll
    for (int d = 1; d < 16; d <<= 1)
#pragma unroll
      for (int j = 0; j < 4; ++j) mx[j] = fmaxf(mx[j], __shfl_xor(mx[j], d));
    float sc[4];
#pragma unroll
    for (int j = 0; j < 4; ++j) {
      float mn = fmaxf(m[j], mx[j]);
      sc[j] = __expf(m[j] - mn);
      m[j] = mn;
    }
    float ps[4] = {0.f, 0.f, 0.f, 0.f};
#pragma unroll
    for (int t = 0; t < 4; ++t)
#pragma unroll
      for (int j = 0; j < 4; ++j) {
        float p = __expf(s[t][j] - m[j]);
        s[t][j] = p;
        ps[j] += p;
      }
#pragma unroll
    for (int d = 1; d < 16; d <<= 1)
#pragma unroll
      for (int j = 0; j < 4; ++j) ps[j] += __shfl_xor(ps[j], d);
#pragma unroll
    for (int j = 0; j < 4; ++j) lsum[j] = lsum[j] * sc[j] + ps[j];
#pragma unroll
    for (int t = 0; t < 4; ++t)
#pragma unroll
      for (int j = 0; j < 4; ++j) o[t][j] *= sc[j];

    // P -> wave-private swizzled LDS, repack to A-fragments
    short* pl = (short*)pls[w];
#pragma unroll
    for (int t = 0; t < 4; ++t)
#pragma unroll
      for (int j = 0; j < 4; ++j) {
        int qr = ((lane >> 4) << 2) + j;
        int kvc = t * 16 + (lane & 15);
        int off = (qr * 128 + kvc * 2) ^ ((qr & 7) << 4);
        *(short*)((char*)pl + off) = (short)f2bf(s[t][j]);
      }
    {
      int rowp = lane & 15;
      int swp = (rowp & 7) << 4;
      bf16x8 pf0 = *(const bf16x8*)((const char*)pl + ((rowp * 128 + (lane >> 4) * 16) ^ swp));
      bf16x8 pf1 = *(const bf16x8*)((const char*)pl + ((rowp * 128 + 64 + (lane >> 4) * 16) ^ swp));
#pragma unroll
      for (int t2 = 0; t2 < 4; ++t2) {
        int rv = t2 * 16 + (lane & 15);
        int swv = (rv & 7) << 4;
        bf16x8 vf0 = *(const bf16x8*)((const char*)vls + ((rv * 128 + (lane >> 4) * 16) ^ swv));
        bf16x8 vf1 = *(const bf16x8*)((const char*)vls + ((rv * 128 + 64 + (lane >> 4) * 16) ^ swv));
        o[t2] = __builtin_amdgcn_mfma_f32_16x16x32_bf16(pf0, vf0, o[t2], 0, 0, 0);
        o[t2] = __builtin_amdgcn_mfma_f32_16x16x32_bf16(pf1, vf1, o[t2], 0, 0, 0);
      }
    }
    __syncthreads();
  }
#pragma unroll
  for (int t2 = 0; t2 < 4; ++t2)
#pragma unroll
    for (int j = 0; j < 4; ++j) {
      int qr = ((lane >> 4) << 2) + j;
      int d = t2 * 16 + (lane & 15);
      float v = o[t2][j] / lsum[j];
      outb[(size_t)(b * SEQ + q0 + qr) * 768 + h * 64 + d] = (short)f2bf(v);
    }
}

extern "C" void kernel_launch(void* const* d_in, const int* in_sizes, int n_in,
                              void* d_out, int out_size, void* d_ws, size_t ws_size,
                              hipStream_t stream) {
  const float* x      = (const float*)d_in[0];
  const float* pos    = (const float*)d_in[1];
  const float* W_qkv  = (const float*)d_in[2];
  const float* b_qkv  = (const float*)d_in[3];
  const float* W_proj = (const float*)d_in[4];
  const float* b_proj = (const float*)d_in[5];
  float* out = (float*)d_out;

  char* ws = (char*)d_ws;
  short* A_hilo  = (short*)(ws);                  // 8192*1536*2 = 25165824
  short* B2t     = (short*)(ws + 25165824);       // 2304*1536*2 =  7077888
  short* qbuf    = (short*)(ws + 32243712);       // 12582912
  short* kbuf    = (short*)(ws + 44826624);       // 12582912
  short* vtbuf   = (short*)(ws + 57409536);       // 12582912
  short* attnbuf = (short*)(ws + 69992448);       // 12582912
  short* wpt     = (short*)(ws + 82575360);       // 768*768*2 = 1179648

  prep_x_kernel<<<6144, 256, 0, stream>>>(x, A_hilo);
  prep_w_kernel<<<dim3(12, 36), 256, 0, stream>>>(W_qkv, B2t);
  prep_wp_kernel<<<dim3(12, 12), 256, 0, stream>>>(W_proj, wpt);
  gemm_kernel<1><<<dim3(18, 64), 256, 0, stream>>>(A_hilo, B2t, b_qkv,
                                                   qbuf, kbuf, vtbuf, nullptr);
  attn_kernel<<<dim3(16, 12, 8), 256, 0, stream>>>(qbuf, kbuf, vtbuf, pos, attnbuf);
  gemm_kernel<2><<<dim3(6, 64), 256, 0, stream>>>(attnbuf, wpt, b_proj,
                                                  nullptr, nullptr, nullptr, out);
}

// Round 2
// 216.295 us; speedup vs baseline: 1.3040x; 1.3040x over previous
//
#include <hip/hip_runtime.h>

#define SEQ   1024
#define HEADS 12
#define CDIM  768
#define BATCH 8

typedef __attribute__((ext_vector_type(8))) short bf16x8;
typedef __attribute__((ext_vector_type(4))) float f32x4;
typedef __attribute__((ext_vector_type(4))) float float4v;
typedef __attribute__((ext_vector_type(4))) short short4v;

__device__ __forceinline__ void gload_lds16(const void* g, void* l) {
  __builtin_amdgcn_global_load_lds(
      (const __attribute__((address_space(1))) unsigned int*)g,
      (__attribute__((address_space(3))) unsigned int*)l, 16, 0, 0);
}

__device__ __forceinline__ unsigned short f2bf(float f) {
  union { float f; unsigned u; } v; v.f = f;
  unsigned r = v.u + 0x7fff + ((v.u >> 16) & 1);
  return (unsigned short)(r >> 16);
}
__device__ __forceinline__ float bf2f(unsigned short b) {
  union { float f; unsigned u; } v; v.u = ((unsigned)b) << 16;
  return v.f;
}

// x [8192,768] f32 -> A [8192,768] bf16
__global__ __launch_bounds__(256) void prep_x_kernel(const float* __restrict__ x,
                                                     short* __restrict__ A) {
  int i = blockIdx.x * 256 + threadIdx.x;      // 8192*192 threads, 4 elems each
  int r = i / 192;
  int c4 = (i % 192) * 4;
  float4v xv = *(const float4v*)(x + (size_t)r * 768 + c4);
  short4v hi;
#pragma unroll
  for (int j = 0; j < 4; ++j) hi[j] = (short)f2bf(xv[j]);
  *(short4v*)(A + (size_t)r * 768 + c4) = hi;
}

// W_qkv [768,2304] f32 -> Bt [2304,768] bf16 transposed
__global__ __launch_bounds__(256) void prep_w_kernel(const float* __restrict__ W,
                                                     short* __restrict__ Bt) {
  __shared__ float tile[64][65];
  int k0 = blockIdx.x * 64;   // over 768
  int n0 = blockIdx.y * 64;   // over 2304
  int t = threadIdx.x;
#pragma unroll
  for (int it = 0; it < 16; ++it) {
    int r = it * 4 + (t >> 6);
    int c = t & 63;
    tile[r][c] = W[(size_t)(k0 + r) * 2304 + n0 + c];
  }
  __syncthreads();
#pragma unroll
  for (int it = 0; it < 16; ++it) {
    int nr = it * 4 + (t >> 6);
    int kc = t & 63;
    Bt[(size_t)(n0 + nr) * 768 + k0 + kc] = (short)f2bf(tile[kc][nr]);
  }
}

// W_proj [768,768] f32 -> Wpt [768,768] bf16 transposed
__global__ __launch_bounds__(256) void prep_wp_kernel(const float* __restrict__ W,
                                                      short* __restrict__ Bt) {
  __shared__ float tile[64][65];
  int k0 = blockIdx.x * 64;
  int n0 = blockIdx.y * 64;
  int t = threadIdx.x;
#pragma unroll
  for (int it = 0; it < 16; ++it) {
    int r = it * 4 + (t >> 6);
    int c = t & 63;
    tile[r][c] = W[(size_t)(k0 + r) * 768 + n0 + c];
  }
  __syncthreads();
#pragma unroll
  for (int it = 0; it < 16; ++it) {
    int nr = it * 4 + (t >> 6);
    int kc = t & 63;
    Bt[(size_t)(n0 + nr) * 768 + k0 + kc] = (short)f2bf(tile[kc][nr]);
  }
}

// pos [12,1024,1024] f32 -> posT [12,1024,1024] bf16, transposed per head:
// posT[h][kv][q] = pos[h][q][kv]
__global__ __launch_bounds__(256) void prep_pos_kernel(const float* __restrict__ P,
                                                       short* __restrict__ PT) {
  __shared__ float tile[64][65];
  int i0 = blockIdx.x * 64;   // q rows
  int j0 = blockIdx.y * 64;   // kv cols
  int h = blockIdx.z;
  const float* Ph = P + (size_t)h * SEQ * SEQ;
  short* PTh = PT + (size_t)h * SEQ * SEQ;
  int t = threadIdx.x;
#pragma unroll
  for (int it = 0; it < 16; ++it) {
    int r = it * 4 + (t >> 6);
    int c = t & 63;
    tile[r][c] = Ph[(size_t)(i0 + r) * SEQ + j0 + c];
  }
  __syncthreads();
#pragma unroll
  for (int it = 0; it < 16; ++it) {
    int r = it * 4 + (t >> 6);   // kv row within tile
    int c = t & 63;              // q col within tile
    PTh[(size_t)(j0 + r) * SEQ + i0 + c] = (short)f2bf(tile[c][r]);
  }
}

// Shared 128x128-tile GEMM, BK=64, K=768, 4 waves, 16x16x32 bf16 MFMA.
// MODE 1: qkv GEMM (N=2304), scatter q/k/vT bf16.
// MODE 2: proj GEMM (N=768), write f32 + bias.
template <int MODE>
__global__ __launch_bounds__(256) void gemm_kernel(
    const short* __restrict__ A, const short* __restrict__ Bt,
    const float* __restrict__ bias,
    short* __restrict__ outQ, short* __restrict__ outK, short* __restrict__ outVT,
    float* __restrict__ outF) {
  const int n0 = blockIdx.x * 128;
  const int m0 = blockIdx.y * 128;
  __shared__ short Als[128 * 64];
  __shared__ short Bls[128 * 64];
  const int tid = threadIdx.x;
  const int lane = tid & 63;
  const int w = tid >> 6;
  const int wr = (w >> 1) * 64;
  const int wc = (w & 1) * 64;
  f32x4 acc[4][4];
#pragma unroll
  for (int mi = 0; mi < 4; ++mi)
#pragma unroll
    for (int ni = 0; ni < 4; ++ni) acc[mi][ni] = (f32x4){0.f, 0.f, 0.f, 0.f};

  for (int k0 = 0; k0 < 768; k0 += 64) {
#pragma unroll
    for (int it = 0; it < 4; ++it) {
      int rbase = it * 32 + w * 8;
      int row = rbase + (lane >> 3);
      int ul = (lane & 7) ^ (row & 7);     // inverse-swizzled global unit
      gload_lds16(A + (size_t)(m0 + row) * 768 + k0 + ul * 8, Als + rbase * 64);
      gload_lds16(Bt + (size_t)(n0 + row) * 768 + k0 + ul * 8, Bls + rbase * 64);
    }
    __syncthreads();
#pragma unroll
    for (int kk = 0; kk < 2; ++kk) {
      bf16x8 af[4], bfv[4];
#pragma unroll
      for (int mi = 0; mi < 4; ++mi) {
        int row = wr + mi * 16 + (lane & 15);
        int off = (row * 128 + kk * 64 + (lane >> 4) * 16) ^ ((row & 7) << 4);
        af[mi] = *(const bf16x8*)((const char*)Als + off);
      }
#pragma unroll
      for (int ni = 0; ni < 4; ++ni) {
        int row = wc + ni * 16 + (lane & 15);
        int off = (row * 128 + kk * 64 + (lane >> 4) * 16) ^ ((row & 7) << 4);
        bfv[ni] = *(const bf16x8*)((const char*)Bls + off);
      }
#pragma unroll
      for (int mi = 0; mi < 4; ++mi)
#pragma unroll
        for (int ni = 0; ni < 4; ++ni)
          acc[mi][ni] = __builtin_amdgcn_mfma_f32_16x16x32_bf16(
              af[mi], bfv[ni], acc[mi][ni], 0, 0, 0);
    }
    __syncthreads();
  }
  // epilogue: C row=(lane>>4)*4+j, col=lane&15 within each 16x16 tile
#pragma unroll
  for (int mi = 0; mi < 4; ++mi)
#pragma unroll
    for (int ni = 0; ni < 4; ++ni)
#pragma unroll
      for (int j = 0; j < 4; ++j) {
        int row = m0 + wr + mi * 16 + ((lane >> 4) << 2) + j;
        int col = n0 + wc + ni * 16 + (lane & 15);
        float v = acc[mi][ni][j] + bias[col];
        if (MODE == 1) {
          int three = col / 768;
          int rem = col - three * 768;
          int h = rem >> 6, d = rem & 63;
          int b = row >> 10, n = row & 1023;
          unsigned short bv = f2bf(v);
          size_t bh = (size_t)(b * 12 + h);
          if (three == 0)      outQ[(bh * 1024 + n) * 64 + d] = (short)bv;
          else if (three == 1) outK[(bh * 1024 + n) * 64 + d] = (short)bv;
          else                 outVT[(bh * 64 + d) * 1024 + n] = (short)bv;
        } else {
          outF[(size_t)row * 768 + col] = v;
        }
      }
}

// Flash attention: grid (16 qblocks, 12 heads, 8 batch), 4 waves x 16 q-rows.
__global__ __launch_bounds__(256) void attn_kernel(
    const short* __restrict__ qb, const short* __restrict__ kb,
    const short* __restrict__ vtb, const short* __restrict__ posT,
    short* __restrict__ outb) {
  const int qblk = blockIdx.x, h = blockIdx.y, b = blockIdx.z;
  const int tid = threadIdx.x, lane = tid & 63, w = tid >> 6;
  const size_t bh = (size_t)(b * 12 + h);
  const short* Q = qb + bh * SEQ * 64;
  const short* K = kb + bh * SEQ * 64;
  const short* VT = vtb + bh * 64 * SEQ;
  const short* PT = posT + (size_t)h * SEQ * SEQ;   // [kv][q] bf16
  const int q0 = qblk * 64 + w * 16;

  __shared__ short kls[64 * 64];
  __shared__ short vls[64 * 64];
  __shared__ short pls[4][16 * 64];

  const int qrow = q0 + (lane & 15);
  bf16x8 qf0 = *(const bf16x8*)(Q + (size_t)qrow * 64 + (lane >> 4) * 8);
  bf16x8 qf1 = *(const bf16x8*)(Q + (size_t)qrow * 64 + 32 + (lane >> 4) * 8);

  f32x4 o[4];
#pragma unroll
  for (int t = 0; t < 4; ++t) o[t] = (f32x4){0.f, 0.f, 0.f, 0.f};
  float m[4] = {-1e30f, -1e30f, -1e30f, -1e30f};
  float lsum[4] = {0.f, 0.f, 0.f, 0.f};

  for (int kv0 = 0; kv0 < SEQ; kv0 += 64) {
#pragma unroll
    for (int it = 0; it < 2; ++it) {
      int rbase = w * 16 + it * 8;
      int row = rbase + (lane >> 3);
      int ul = (lane & 7) ^ (row & 7);
      gload_lds16(K + (size_t)(kv0 + row) * 64 + ul * 8, kls + rbase * 64);
      gload_lds16(VT + (size_t)row * SEQ + kv0 + ul * 8, vls + rbase * 64);
    }
    __syncthreads();

    f32x4 s[4];
#pragma unroll
    for (int t = 0; t < 4; ++t) {
      int row = t * 16 + (lane & 15);
      int sw = (row & 7) << 4;
      bf16x8 kf0 = *(const bf16x8*)((const char*)kls + ((row * 128 + (lane >> 4) * 16) ^ sw));
      bf16x8 kf1 = *(const bf16x8*)((const char*)kls + ((row * 128 + 64 + (lane >> 4) * 16) ^ sw));
      f32x4 z = (f32x4){0.f, 0.f, 0.f, 0.f};
      z = __builtin_amdgcn_mfma_f32_16x16x32_bf16(qf0, kf0, z, 0, 0, 0);
      s[t] = __builtin_amdgcn_mfma_f32_16x16x32_bf16(qf1, kf1, z, 0, 0, 0);
    }
    // pos add: posT[kv][q] bf16, 4 consecutive q per lane (j=0..3)
#pragma unroll
    for (int t = 0; t < 4; ++t) {
      short4v pv4 = *(const short4v*)(PT + (size_t)(kv0 + t * 16 + (lane & 15)) * SEQ
                                      + q0 + ((lane >> 4) << 2));
#pragma unroll
      for (int j = 0; j < 4; ++j)
        s[t][j] = (s[t][j] + bf2f((unsigned short)pv4[j])) * 0.125f;
    }
    float mx[4];
#pragma unroll
    for (int j = 0; j < 4; ++j)
      mx[j] = fmaxf(fmaxf(s[0][j], s[1][j]), fmaxf(s[2][j], s[3][j]));
#pragma unroll
    for (int d = 1; d < 16; d <<= 1)
#pragma unroll
      for (int j = 0; j < 4; ++j) mx[j] = fmaxf(mx[j], __shfl_xor(mx[j], d));
    float sc[4];
#pragma unroll
    for (int j = 0; j < 4; ++j) {
      float mn = fmaxf(m[j], mx[j]);
      sc[j] = __expf(m[j] - mn);
      m[j] = mn;
    }
    float ps[4] = {0.f, 0.f, 0.f, 0.f};
#pragma unroll
    for (int t = 0; t < 4; ++t)
#pragma unroll
      for (int j = 0; j < 4; ++j) {
        float p = __expf(s[t][j] - m[j]);
        s[t][j] = p;
        ps[j] += p;
      }
#pragma unroll
    for (int d = 1; d < 16; d <<= 1)
#pragma unroll
      for (int j = 0; j < 4; ++j) ps[j] += __shfl_xor(ps[j], d);
#pragma unroll
    for (int j = 0; j < 4; ++j) lsum[j] = lsum[j] * sc[j] + ps[j];
#pragma unroll
    for (int t = 0; t < 4; ++t)
#pragma unroll
      for (int j = 0; j < 4; ++j) o[t][j] *= sc[j];

    // P -> wave-private swizzled LDS, repack to A-fragments
    short* pl = (short*)pls[w];
#pragma unroll
    for (int t = 0; t < 4; ++t)
#pragma unroll
      for (int j = 0; j < 4; ++j) {
        int qr = ((lane >> 4) << 2) + j;
        int kvc = t * 16 + (lane & 15);
        int off = (qr * 128 + kvc * 2) ^ ((qr & 7) << 4);
        *(short*)((char*)pl + off) = (short)f2bf(s[t][j]);
      }
    {
      int rowp = lane & 15;
      int swp = (rowp & 7) << 4;
      bf16x8 pf0 = *(const bf16x8*)((const char*)pl + ((rowp * 128 + (lane >> 4) * 16) ^ swp));
      bf16x8 pf1 = *(const bf16x8*)((const char*)pl + ((rowp * 128 + 64 + (lane >> 4) * 16) ^ swp));
#pragma unroll
      for (int t2 = 0; t2 < 4; ++t2) {
        int rv = t2 * 16 + (lane & 15);
        int swv = (rv & 7) << 4;
        bf16x8 vf0 = *(const bf16x8*)((const char*)vls + ((rv * 128 + (lane >> 4) * 16) ^ swv));
        bf16x8 vf1 = *(const bf16x8*)((const char*)vls + ((rv * 128 + 64 + (lane >> 4) * 16) ^ swv));
        o[t2] = __builtin_amdgcn_mfma_f32_16x16x32_bf16(pf0, vf0, o[t2], 0, 0, 0);
        o[t2] = __builtin_amdgcn_mfma_f32_16x16x32_bf16(pf1, vf1, o[t2], 0, 0, 0);
      }
    }
    __syncthreads();
  }
#pragma unroll
  for (int t2 = 0; t2 < 4; ++t2)
#pragma unroll
    for (int j = 0; j < 4; ++j) {
      int qr = ((lane >> 4) << 2) + j;
      int d = t2 * 16 + (lane & 15);
      float v = o[t2][j] / lsum[j];
      outb[(size_t)(b * SEQ + q0 + qr) * 768 + h * 64 + d] = (short)f2bf(v);
    }
}

extern "C" void kernel_launch(void* const* d_in, const int* in_sizes, int n_in,
                              void* d_out, int out_size, void* d_ws, size_t ws_size,
                              hipStream_t stream) {
  const float* x      = (const float*)d_in[0];
  const float* pos    = (const float*)d_in[1];
  const float* W_qkv  = (const float*)d_in[2];
  const float* b_qkv  = (const float*)d_in[3];
  const float* W_proj = (const float*)d_in[4];
  const float* b_proj = (const float*)d_in[5];
  float* out = (float*)d_out;

  char* ws = (char*)d_ws;
  // A (x bf16) is consumed by gemm<1> before attn writes attnbuf -> alias them.
  short* A       = (short*)(ws);                  // 8192*768*2   = 12,582,912
  short* attnbuf = (short*)(ws);                  // alias of A
  short* Bt      = (short*)(ws + 12582912);       // 2304*768*2   =  3,538,944
  short* wpt     = (short*)(ws + 16121856);       // 768*768*2    =  1,179,648
  short* qbuf    = (short*)(ws + 17301504);       // 12,582,912
  short* kbuf    = (short*)(ws + 29884416);       // 12,582,912
  short* vtbuf   = (short*)(ws + 42467328);       // 12,582,912
  short* posT    = (short*)(ws + 55050240);       // 12*1024*1024*2 = 25,165,824
  // total: 80,216,064 bytes

  prep_x_kernel<<<6144, 256, 0, stream>>>(x, A);
  prep_w_kernel<<<dim3(12, 36), 256, 0, stream>>>(W_qkv, Bt);
  prep_wp_kernel<<<dim3(12, 12), 256, 0, stream>>>(W_proj, wpt);
  prep_pos_kernel<<<dim3(16, 16, 12), 256, 0, stream>>>(pos, posT);
  gemm_kernel<1><<<dim3(18, 64), 256, 0, stream>>>(A, Bt, b_qkv,
                                                   qbuf, kbuf, vtbuf, nullptr);
  attn_kernel<<<dim3(16, 12, 8), 256, 0, stream>>>(qbuf, kbuf, vtbuf, posT, attnbuf);
  gemm_kernel<2><<<dim3(6, 64), 256, 0, stream>>>(attnbuf, wpt, b_proj,
                                                  nullptr, nullptr, nullptr, out);
}

// Round 3
// 200.592 us; speedup vs baseline: 1.4061x; 1.0783x over previous
//
#include <hip/hip_runtime.h>

#define SEQ   1024
#define HEADS 12
#define CDIM  768
#define BATCH 8

// 0.125 * log2(e): folds the 1/sqrt(64) score scale and the exp->exp2 change
#define QSCALE 0.18033688011112042f

typedef __attribute__((ext_vector_type(8))) short bf16x8;
typedef __attribute__((ext_vector_type(4))) float f32x4;
typedef __attribute__((ext_vector_type(4))) float float4v;
typedef __attribute__((ext_vector_type(4))) short short4v;

__device__ __forceinline__ void gload_lds16(const void* g, void* l) {
  __builtin_amdgcn_global_load_lds(
      (const __attribute__((address_space(1))) unsigned int*)g,
      (__attribute__((address_space(3))) unsigned int*)l, 16, 0, 0);
}

__device__ __forceinline__ unsigned short f2bf(float f) {
  union { float f; unsigned u; } v; v.f = f;
  unsigned r = v.u + 0x7fff + ((v.u >> 16) & 1);
  return (unsigned short)(r >> 16);
}

// pack two f32 -> u32 of 2x bf16 (lo = a, hi = b); no builtin on gfx950
__device__ __forceinline__ unsigned cvtpk(float a, float b) {
  unsigned r;
  asm("v_cvt_pk_bf16_f32 %0, %1, %2" : "=v"(r) : "v"(a), "v"(b));
  return r;
}

// x [8192,768] f32 -> A [8192,768] bf16
__global__ __launch_bounds__(256) void prep_x_kernel(const float* __restrict__ x,
                                                     short* __restrict__ A) {
  int i = blockIdx.x * 256 + threadIdx.x;
  int r = i / 192;
  int c4 = (i % 192) * 4;
  float4v xv = *(const float4v*)(x + (size_t)r * 768 + c4);
  short4v hi;
#pragma unroll
  for (int j = 0; j < 4; ++j) hi[j] = (short)f2bf(xv[j]);
  *(short4v*)(A + (size_t)r * 768 + c4) = hi;
}

// W_qkv [768,2304] f32 -> Bt [2304,768] bf16 transposed
__global__ __launch_bounds__(256) void prep_w_kernel(const float* __restrict__ W,
                                                     short* __restrict__ Bt) {
  __shared__ float tile[64][65];
  int k0 = blockIdx.x * 64;
  int n0 = blockIdx.y * 64;
  int t = threadIdx.x;
#pragma unroll
  for (int it = 0; it < 16; ++it) {
    int r = it * 4 + (t >> 6);
    int c = t & 63;
    tile[r][c] = W[(size_t)(k0 + r) * 2304 + n0 + c];
  }
  __syncthreads();
#pragma unroll
  for (int it = 0; it < 16; ++it) {
    int nr = it * 4 + (t >> 6);
    int kc = t & 63;
    Bt[(size_t)(n0 + nr) * 768 + k0 + kc] = (short)f2bf(tile[kc][nr]);
  }
}

// W_proj [768,768] f32 -> Wpt [768,768] bf16 transposed
__global__ __launch_bounds__(256) void prep_wp_kernel(const float* __restrict__ W,
                                                      short* __restrict__ Bt) {
  __shared__ float tile[64][65];
  int k0 = blockIdx.x * 64;
  int n0 = blockIdx.y * 64;
  int t = threadIdx.x;
#pragma unroll
  for (int it = 0; it < 16; ++it) {
    int r = it * 4 + (t >> 6);
    int c = t & 63;
    tile[r][c] = W[(size_t)(k0 + r) * 768 + n0 + c];
  }
  __syncthreads();
#pragma unroll
  for (int it = 0; it < 16; ++it) {
    int nr = it * 4 + (t >> 6);
    int kc = t & 63;
    Bt[(size_t)(n0 + nr) * 768 + k0 + kc] = (short)f2bf(tile[kc][nr]);
  }
}

// Shared 128x128-tile GEMM, BK=64, K=768, 4 waves, 16x16x32 bf16 MFMA.
// MODE 1: qkv GEMM (N=2304), scatter q(*QSCALE)/k/vT bf16.
// MODE 2: proj GEMM (N=768), write f32 + bias.
template <int MODE>
__global__ __launch_bounds__(256) void gemm_kernel(
    const short* __restrict__ A, const short* __restrict__ Bt,
    const float* __restrict__ bias,
    short* __restrict__ outQ, short* __restrict__ outK, short* __restrict__ outVT,
    float* __restrict__ outF) {
  const int n0 = blockIdx.x * 128;
  const int m0 = blockIdx.y * 128;
  __shared__ short Als[128 * 64];
  __shared__ short Bls[128 * 64];
  const int tid = threadIdx.x;
  const int lane = tid & 63;
  const int w = tid >> 6;
  const int wr = (w >> 1) * 64;
  const int wc = (w & 1) * 64;
  f32x4 acc[4][4];
#pragma unroll
  for (int mi = 0; mi < 4; ++mi)
#pragma unroll
    for (int ni = 0; ni < 4; ++ni) acc[mi][ni] = (f32x4){0.f, 0.f, 0.f, 0.f};

  for (int k0 = 0; k0 < 768; k0 += 64) {
#pragma unroll
    for (int it = 0; it < 4; ++it) {
      int rbase = it * 32 + w * 8;
      int row = rbase + (lane >> 3);
      int ul = (lane & 7) ^ (row & 7);
      gload_lds16(A + (size_t)(m0 + row) * 768 + k0 + ul * 8, Als + rbase * 64);
      gload_lds16(Bt + (size_t)(n0 + row) * 768 + k0 + ul * 8, Bls + rbase * 64);
    }
    __syncthreads();
#pragma unroll
    for (int kk = 0; kk < 2; ++kk) {
      bf16x8 af[4], bfv[4];
#pragma unroll
      for (int mi = 0; mi < 4; ++mi) {
        int row = wr + mi * 16 + (lane & 15);
        int off = (row * 128 + kk * 64 + (lane >> 4) * 16) ^ ((row & 7) << 4);
        af[mi] = *(const bf16x8*)((const char*)Als + off);
      }
#pragma unroll
      for (int ni = 0; ni < 4; ++ni) {
        int row = wc + ni * 16 + (lane & 15);
        int off = (row * 128 + kk * 64 + (lane >> 4) * 16) ^ ((row & 7) << 4);
        bfv[ni] = *(const bf16x8*)((const char*)Bls + off);
      }
#pragma unroll
      for (int mi = 0; mi < 4; ++mi)
#pragma unroll
        for (int ni = 0; ni < 4; ++ni)
          acc[mi][ni] = __builtin_amdgcn_mfma_f32_16x16x32_bf16(
              af[mi], bfv[ni], acc[mi][ni], 0, 0, 0);
    }
    __syncthreads();
  }
#pragma unroll
  for (int mi = 0; mi < 4; ++mi)
#pragma unroll
    for (int ni = 0; ni < 4; ++ni)
#pragma unroll
      for (int j = 0; j < 4; ++j) {
        int row = m0 + wr + mi * 16 + ((lane >> 4) << 2) + j;
        int col = n0 + wc + ni * 16 + (lane & 15);
        float v = acc[mi][ni][j] + bias[col];
        if (MODE == 1) {
          int three = col / 768;
          int rem = col - three * 768;
          int h = rem >> 6, d = rem & 63;
          int b = row >> 10, n = row & 1023;
          size_t bh = (size_t)(b * 12 + h);
          if (three == 0)      outQ[(bh * 1024 + n) * 64 + d] = (short)f2bf(v * QSCALE);
          else if (three == 1) outK[(bh * 1024 + n) * 64 + d] = (short)f2bf(v);
          else                 outVT[(bh * 64 + d) * 1024 + n] = (short)f2bf(v);
        } else {
          outF[(size_t)row * 768 + col] = v;
        }
      }
}

// Flash attention, swapped-operand QK^T (P^T layout), in-register softmax,
// cvt_pk + bpermute P->B-frag, 2-phase double-buffered K/V staging.
// grid (16 qblocks, 12 heads, 8 batch), 4 waves x 16 q-rows.
__global__ __launch_bounds__(256) void attn_kernel(
    const short* __restrict__ qb, const short* __restrict__ kb,
    const short* __restrict__ vtb, const float* __restrict__ pos,
    short* __restrict__ outb) {
  const int qblk = blockIdx.x, h = blockIdx.y, b = blockIdx.z;
  const int tid = threadIdx.x, lane = tid & 63, w = tid >> 6;
  const int c = lane & 15, g = lane >> 4;
  const size_t bh = (size_t)(b * 12 + h);
  const short* Q = qb + bh * SEQ * 64;
  const short* K = kb + bh * SEQ * 64;
  const short* VT = vtb + bh * 64 * SEQ;
  const float* Ph = pos + (size_t)h * SEQ * SEQ;
  const int q0w = qblk * 64 + w * 16;

  __shared__ short kls[2 * 64 * 64];
  __shared__ short vls[2 * 64 * 64];

  // Q as B-operand: col = q = c, k = d = g*8..; Q was pre-scaled by QSCALE.
  bf16x8 qf0 = *(const bf16x8*)(Q + (size_t)(q0w + c) * 64 + g * 8);
  bf16x8 qf1 = *(const bf16x8*)(Q + (size_t)(q0w + c) * 64 + 32 + g * 8);

  f32x4 o[4];   // O^T accum: d = t2*16 + g*4 + j, q = c
#pragma unroll
  for (int t2 = 0; t2 < 4; ++t2) o[t2] = (f32x4){0.f, 0.f, 0.f, 0.f};
  float m_r = -1e30f, lsum = 0.f;

  auto STAGE = [&](int buf, int kv0) {
#pragma unroll
    for (int it = 0; it < 2; ++it) {
      int rbase = w * 16 + it * 8;
      int row = rbase + (lane >> 3);
      int ul = (lane & 7) ^ (row & 7);
      gload_lds16(K + (size_t)(kv0 + row) * 64 + ul * 8, kls + buf * 4096 + rbase * 64);
      gload_lds16(VT + (size_t)row * SEQ + kv0 + ul * 8, vls + buf * 4096 + rbase * 64);
    }
  };

  STAGE(0, 0);
  asm volatile("s_waitcnt vmcnt(0)" ::: "memory");
  __builtin_amdgcn_s_barrier();
  asm volatile("" ::: "memory");

  for (int ti = 0; ti < 16; ++ti) {
    const int kv0 = ti * 64;
    const int cur = ti & 1;
    if (ti < 15) STAGE(cur ^ 1, kv0 + 64);   // prefetch next tile (in flight)

    const short* kc = kls + cur * 4096;
    const short* vc = vls + cur * 4096;

    // QK^T swapped: A = K (rows = kv), B = Q (cols = q).
    // s[t]: row = kv_local = t*16 + g*4 + j, col = q = c.
    f32x4 s[4];
#pragma unroll
    for (int t = 0; t < 4; ++t) {
      int row = t * 16 + c;
      int sw = (row & 7) << 4;
      bf16x8 kf0 = *(const bf16x8*)((const char*)kc + ((row * 128 + g * 16) ^ sw));
      bf16x8 kf1 = *(const bf16x8*)((const char*)kc + ((row * 128 + 64 + g * 16) ^ sw));
      f32x4 z = (f32x4){0.f, 0.f, 0.f, 0.f};
      z = __builtin_amdgcn_mfma_f32_16x16x32_bf16(kf0, qf0, z, 0, 0, 0);
      s[t] = __builtin_amdgcn_mfma_f32_16x16x32_bf16(kf1, qf1, z, 0, 0, 0);
    }
    // pos add (raw f32, fma with QSCALE): 4 consecutive kv per lane per t
#pragma unroll
    for (int t = 0; t < 4; ++t) {
      float4v pv = *(const float4v*)(Ph + (size_t)(q0w + c) * SEQ + kv0 + t * 16 + g * 4);
#pragma unroll
      for (int j = 0; j < 4; ++j) s[t][j] = fmaf(pv[j], QSCALE, s[t][j]);
    }

    // row max over kv: 16 in-register + cross-group (lanes c, c+16, c+32, c+48)
    float t0 = fmaxf(fmaxf(s[0][0], s[0][1]), fmaxf(s[0][2], s[0][3]));
    float t1 = fmaxf(fmaxf(s[1][0], s[1][1]), fmaxf(s[1][2], s[1][3]));
    float t2m = fmaxf(fmaxf(s[2][0], s[2][1]), fmaxf(s[2][2], s[2][3]));
    float t3 = fmaxf(fmaxf(s[3][0], s[3][1]), fmaxf(s[3][2], s[3][3]));
    float pmax = fmaxf(fmaxf(t0, t1), fmaxf(t2m, t3));
    pmax = fmaxf(pmax, __shfl_xor(pmax, 16));
    pmax = fmaxf(pmax, __shfl_xor(pmax, 32));

    // defer-max (T13): skip O/lsum rescale when growth <= 8 (log2 domain)
    if (!__all(pmax - m_r <= 8.0f)) {
      float mnew = fmaxf(m_r, pmax);
      float sc = exp2f(m_r - mnew);
      lsum *= sc;
#pragma unroll
      for (int t2 = 0; t2 < 4; ++t2)
#pragma unroll
        for (int j = 0; j < 4; ++j) o[t2][j] *= sc;
      m_r = mnew;
    }

    float ps = 0.f;
#pragma unroll
    for (int t = 0; t < 4; ++t)
#pragma unroll
      for (int j = 0; j < 4; ++j) {
        float p = exp2f(s[t][j] - m_r);
        s[t][j] = p;
        ps += p;
      }
    ps += __shfl_xor(ps, 16);
    ps += __shfl_xor(ps, 32);
    lsum += ps;

    // pack P^T to bf16 pairs: pk[t][jp] = (p[t][2jp] | p[t][2jp+1]<<16)
    unsigned pk00 = cvtpk(s[0][0], s[0][1]), pk01 = cvtpk(s[0][2], s[0][3]);
    unsigned pk10 = cvtpk(s[1][0], s[1][1]), pk11 = cvtpk(s[1][2], s[1][3]);
    unsigned pk20 = cvtpk(s[2][0], s[2][1]), pk21 = cvtpk(s[2][2], s[2][3]);
    unsigned pk30 = cvtpk(s[3][0], s[3][1]), pk31 = cvtpk(s[3][2], s[3][3]);

    // redistribute to PV B-frags: lane needs kv = m*32 + g*8 + i (i=0..7)
    // source: t' = 2m + (g>>1), g' = (2g + (i>>2)) & 3, j = i&3
    int src0 = ((g * 2) & 3) * 16 + c;
    int src1 = src0 + 16;
    int hi = g >> 1;
    union { bf16x8 v; unsigned u[4]; } pb0, pb1;
    {
      unsigned a0 = (unsigned)__shfl((int)pk00, src0), b0 = (unsigned)__shfl((int)pk10, src0);
      unsigned a1 = (unsigned)__shfl((int)pk01, src0), b1 = (unsigned)__shfl((int)pk11, src0);
      unsigned a2 = (unsigned)__shfl((int)pk00, src1), b2 = (unsigned)__shfl((int)pk10, src1);
      unsigned a3 = (unsigned)__shfl((int)pk01, src1), b3 = (unsigned)__shfl((int)pk11, src1);
      pb0.u[0] = hi ? b0 : a0; pb0.u[1] = hi ? b1 : a1;
      pb0.u[2] = hi ? b2 : a2; pb0.u[3] = hi ? b3 : a3;
    }
    {
      unsigned a0 = (unsigned)__shfl((int)pk20, src0), b0 = (unsigned)__shfl((int)pk30, src0);
      unsigned a1 = (unsigned)__shfl((int)pk21, src0), b1 = (unsigned)__shfl((int)pk31, src0);
      unsigned a2 = (unsigned)__shfl((int)pk20, src1), b2 = (unsigned)__shfl((int)pk30, src1);
      unsigned a3 = (unsigned)__shfl((int)pk21, src1), b3 = (unsigned)__shfl((int)pk31, src1);
      pb1.u[0] = hi ? b0 : a0; pb1.u[1] = hi ? b1 : a1;
      pb1.u[2] = hi ? b2 : a2; pb1.u[3] = hi ? b3 : a3;
    }

    // PV: O^T += V^T(rows=d) x P^T(cols=q); A = V^T frag, B = pb
#pragma unroll
    for (int t2 = 0; t2 < 4; ++t2) {
      int rv = t2 * 16 + c;
      int swv = (rv & 7) << 4;
      bf16x8 vf0 = *(const bf16x8*)((const char*)vc + ((rv * 128 + g * 16) ^ swv));
      bf16x8 vf1 = *(const bf16x8*)((const char*)vc + ((rv * 128 + 64 + g * 16) ^ swv));
      o[t2] = __builtin_amdgcn_mfma_f32_16x16x32_bf16(vf0, pb0.v, o[t2], 0, 0, 0);
      o[t2] = __builtin_amdgcn_mfma_f32_16x16x32_bf16(vf1, pb1.v, o[t2], 0, 0, 0);
    }

    asm volatile("s_waitcnt vmcnt(0)" ::: "memory");
    __builtin_amdgcn_s_barrier();
    asm volatile("" ::: "memory");
  }

  float inv = 1.0f / lsum;
  size_t obase = (size_t)(b * SEQ + q0w + c) * 768 + h * 64;
#pragma unroll
  for (int t2 = 0; t2 < 4; ++t2) {
    short4v ov;
#pragma unroll
    for (int j = 0; j < 4; ++j) ov[j] = (short)f2bf(o[t2][j] * inv);
    *(short4v*)(outb + obase + t2 * 16 + g * 4) = ov;
  }
}

extern "C" void kernel_launch(void* const* d_in, const int* in_sizes, int n_in,
                              void* d_out, int out_size, void* d_ws, size_t ws_size,
                              hipStream_t stream) {
  const float* x      = (const float*)d_in[0];
  const float* pos    = (const float*)d_in[1];
  const float* W_qkv  = (const float*)d_in[2];
  const float* b_qkv  = (const float*)d_in[3];
  const float* W_proj = (const float*)d_in[4];
  const float* b_proj = (const float*)d_in[5];
  float* out = (float*)d_out;

  char* ws = (char*)d_ws;
  short* A       = (short*)(ws);                  // 12,582,912 (consumed by gemm<1>)
  short* attnbuf = (short*)(ws);                  // alias of A (written after)
  short* Bt      = (short*)(ws + 12582912);       //  3,538,944
  short* wpt     = (short*)(ws + 16121856);       //  1,179,648
  short* qbuf    = (short*)(ws + 17301504);       // 12,582,912
  short* kbuf    = (short*)(ws + 29884416);       // 12,582,912
  short* vtbuf   = (short*)(ws + 42467328);       // 12,582,912
  // total: 55,050,240 bytes

  prep_x_kernel<<<6144, 256, 0, stream>>>(x, A);
  prep_w_kernel<<<dim3(12, 36), 256, 0, stream>>>(W_qkv, Bt);
  prep_wp_kernel<<<dim3(12, 12), 256, 0, stream>>>(W_proj, wpt);
  gemm_kernel<1><<<dim3(18, 64), 256, 0, stream>>>(A, Bt, b_qkv,
                                                   qbuf, kbuf, vtbuf, nullptr);
  attn_kernel<<<dim3(16, 12, 8), 256, 0, stream>>>(qbuf, kbuf, vtbuf, pos, attnbuf);
  gemm_kernel<2><<<dim3(6, 64), 256, 0, stream>>>(attnbuf, wpt, b_proj,
                                                  nullptr, nullptr, nullptr, out);
}